// Round 13
// baseline (10613.013 us; speedup 1.0000x reference)
//
#include <hip/hip_runtime.h>

#define N0 16384
#define N1 4096
#define N2 1024
#define E0C 131072
#define FIN 384
#define HF 512

// ---------------- helpers ----------------
__device__ inline float4 f4fma(float w, const float4 v, float4 a) {
  a.x = fmaf(w, v.x, a.x); a.y = fmaf(w, v.y, a.y);
  a.z = fmaf(w, v.z, a.z); a.w = fmaf(w, v.w, a.w);
  return a;
}

// ---------------- CSR build for level-0 random graph ----------------
__global__ __launch_bounds__(256)
void count_deg(const int* __restrict__ dst, int* __restrict__ cnt, int E) {
  int e = blockIdx.x * 256 + threadIdx.x;
  if (e < E) atomicAdd(&cnt[dst[e]], 1);
}

__global__ __launch_bounds__(1024)
void scan_offsets(const int* __restrict__ cnt, int* __restrict__ offs,
                  float* __restrict__ dinv) {
  __shared__ int ts[1024];
  const int t = threadIdx.x;
  int local[16];
  int sum = 0;
  #pragma unroll
  for (int j = 0; j < 16; ++j) { local[j] = cnt[t * 16 + j]; sum += local[j]; }
  ts[t] = sum;
  __syncthreads();
  for (int off = 1; off < 1024; off <<= 1) {
    int v = (t >= off) ? ts[t - off] : 0;
    __syncthreads();
    ts[t] += v;
    __syncthreads();
  }
  int run = ts[t] - sum;
  #pragma unroll
  for (int j = 0; j < 16; ++j) {
    offs[t * 16 + j] = run;
    dinv[t * 16 + j] = 1.0f / sqrtf((float)local[j] + 2.0f);
    run += local[j];
  }
  if (t == 1023) offs[N0] = run;
}

__global__ __launch_bounds__(256)
void fill_csr(const int* __restrict__ src, const int* __restrict__ dst,
              const int* __restrict__ offs, int* __restrict__ cursor,
              int* __restrict__ srcl, int E) {
  int e = blockIdx.x * 256 + threadIdx.x;
  if (e < E) {
    int d = dst[e];
    int p = atomicAdd(&cursor[d], 1);
    srcl[offs[d] + p] = src[e];
  }
}

// ---------------- fp32 GEMM ----------------
template<int BM, int BN, int BK>
__global__ __launch_bounds__(256)
void gemm_f32(const float* __restrict__ A, const float* __restrict__ W,
              const float* __restrict__ bias, float* __restrict__ C,
              int M, int N, int K, int addBias) {
  __shared__ float As[BK][BM + 4];
  __shared__ float Ws[BK][BN];
  const int tid = threadIdx.x;
  const int bm = blockIdx.x * BM;
  const int bn = blockIdx.y * BN;
  const int tx = tid & 15;
  const int ty = tid >> 4;
  float acc[8][4];
  #pragma unroll
  for (int i = 0; i < 8; ++i)
    #pragma unroll
    for (int j = 0; j < 4; ++j) acc[i][j] = 0.f;

  for (int k0 = 0; k0 < K; k0 += BK) {
    #pragma unroll
    for (int h = 0; h < (BM * BK) / (256 * 4); ++h) {
      int q = tid + h * 256;
      int r = q >> 2;
      int c = (q & 3) << 2;
      float4 v = *(const float4*)(A + (size_t)(bm + r) * K + k0 + c);
      As[c][r] = v.x; As[c + 1][r] = v.y; As[c + 2][r] = v.z; As[c + 3][r] = v.w;
    }
    {
      int kk = tid >> 4;
      int n = (tid & 15) << 2;
      *(float4*)(&Ws[kk][n]) = *(const float4*)(W + (size_t)(k0 + kk) * N + bn + n);
    }
    __syncthreads();
    #pragma unroll
    for (int kk = 0; kk < BK; ++kk) {
      float4 b4 = *(const float4*)(&Ws[kk][tx << 2]);
      float4 a0 = *(const float4*)(&As[kk][ty << 3]);
      float4 a1 = *(const float4*)(&As[kk][(ty << 3) + 4]);
      float a[8] = {a0.x, a0.y, a0.z, a0.w, a1.x, a1.y, a1.z, a1.w};
      float b[4] = {b4.x, b4.y, b4.z, b4.w};
      #pragma unroll
      for (int i = 0; i < 8; ++i)
        #pragma unroll
        for (int j = 0; j < 4; ++j)
          acc[i][j] = fmaf(a[i], b[j], acc[i][j]);
    }
    __syncthreads();
  }
  #pragma unroll
  for (int i = 0; i < 8; ++i) {
    int row = bm + (ty << 3) + i;
    float4 o = {acc[i][0], acc[i][1], acc[i][2], acc[i][3]};
    if (addBias) {
      const float4 bb = *(const float4*)(bias + bn + (tx << 2));
      o.x += bb.x; o.y += bb.y; o.z += bb.z; o.w += bb.w;
    }
    *(float4*)(C + (size_t)row * N + bn + (tx << 2)) = o;
  }
}

// ---------------- GCN aggregation (CSR) ----------------
__global__ __launch_bounds__(256)
void gcn_agg_csr(const float* __restrict__ h, const int* __restrict__ offs,
                 const int* __restrict__ srcl, const float* __restrict__ dinv,
                 const float* __restrict__ bias, float* __restrict__ out, int n) {
  const int wid = threadIdx.x >> 6, lane = threadIdx.x & 63;
  const int node = blockIdx.x * 4 + wid;
  if (node >= n) return;
  const float di = dinv[node];
  const int s0 = offs[node], s1 = offs[node + 1];
  float4 a0 = {0, 0, 0, 0}, a1 = {0, 0, 0, 0};
  for (int e = s0; e < s1; ++e) {
    const int s = srcl[e];
    const float w = dinv[s] * di;
    const float4* r = (const float4*)(h + (size_t)s * HF);
    a0 = f4fma(w, r[lane], a0);
    a1 = f4fma(w, r[64 + lane], a1);
  }
  const float sw = 2.0f * di * di;
  const float4* rs = (const float4*)(h + (size_t)node * HF);
  a0 = f4fma(sw, rs[lane], a0);
  a1 = f4fma(sw, rs[64 + lane], a1);
  const float4 b0 = *(const float4*)(bias + (lane << 2));
  const float4 b1 = *(const float4*)(bias + 256 + (lane << 2));
  a0.x = fmaxf(a0.x + b0.x, 0.f); a0.y = fmaxf(a0.y + b0.y, 0.f);
  a0.z = fmaxf(a0.z + b0.z, 0.f); a0.w = fmaxf(a0.w + b0.w, 0.f);
  a1.x = fmaxf(a1.x + b1.x, 0.f); a1.y = fmaxf(a1.y + b1.y, 0.f);
  a1.z = fmaxf(a1.z + b1.z, 0.f); a1.w = fmaxf(a1.w + b1.w, 0.f);
  float4* o = (float4*)(out + (size_t)node * HF);
  o[lane] = a0; o[64 + lane] = a1;
}

// ---------------- GCN aggregation (kNN) ----------------
template<int K>
__global__ __launch_bounds__(256)
void gcn_agg_knn(const float* __restrict__ h, const int* __restrict__ nbr,
                 const float* __restrict__ bias, float* __restrict__ out, int n) {
  const int wid = threadIdx.x >> 6, lane = threadIdx.x & 63;
  const int node = blockIdx.x * 4 + wid;
  if (node >= n) return;
  const float di = 1.0f / sqrtf((float)(K + 2));
  const float w = di * di;
  float4 a0 = {0, 0, 0, 0}, a1 = {0, 0, 0, 0};
  #pragma unroll
  for (int j = 0; j < K; ++j) {
    const int s = nbr[node * K + j];
    const float4* r = (const float4*)(h + (size_t)s * HF);
    a0 = f4fma(w, r[lane], a0);
    a1 = f4fma(w, r[64 + lane], a1);
  }
  const float sw = 2.0f * di * di;
  const float4* rs = (const float4*)(h + (size_t)node * HF);
  a0 = f4fma(sw, rs[lane], a0);
  a1 = f4fma(sw, rs[64 + lane], a1);
  const float4 b0 = *(const float4*)(bias + (lane << 2));
  const float4 b1 = *(const float4*)(bias + 256 + (lane << 2));
  a0.x = fmaxf(a0.x + b0.x, 0.f); a0.y = fmaxf(a0.y + b0.y, 0.f);
  a0.z = fmaxf(a0.z + b0.z, 0.f); a0.w = fmaxf(a0.w + b0.w, 0.f);
  a1.x = fmaxf(a1.x + b1.x, 0.f); a1.y = fmaxf(a1.y + b1.y, 0.f);
  a1.z = fmaxf(a1.z + b1.z, 0.f); a1.w = fmaxf(a1.w + b1.w, 0.f);
  float4* o = (float4*)(out + (size_t)node * HF);
  o[lane] = a0; o[64 + lane] = a1;
}

// ---------------- spatial binning (counting sort into Morton cells) ----------------
__device__ __forceinline__ unsigned part1by1(unsigned x) {
  x &= 0xFFFFu;
  x = (x | (x << 8)) & 0x00FF00FFu;
  x = (x | (x << 4)) & 0x0F0F0F0Fu;
  x = (x | (x << 2)) & 0x33333333u;
  x = (x | (x << 1)) & 0x55555555u;
  return x;
}

__global__ __launch_bounds__(256)
void bin_hist(const float* __restrict__ pos, int* __restrict__ cid,
              int* __restrict__ hist, int n) {
  int i = blockIdx.x * 256 + threadIdx.x;
  if (i >= n) return;
  float x = pos[2 * i], y = pos[2 * i + 1];
  int cxi = (int)(x * 0.32f); cxi = cxi < 0 ? 0 : (cxi > 31 ? 31 : cxi);
  int cyi = (int)(y * 0.32f); cyi = cyi < 0 ? 0 : (cyi > 31 ? 31 : cyi);
  int c = (int)(part1by1((unsigned)cxi) | (part1by1((unsigned)cyi) << 1));
  cid[i] = c;
  atomicAdd(&hist[c], 1);
}

__global__ __launch_bounds__(1024)
void bin_scan(const int* __restrict__ hist, int* __restrict__ offs) {
  __shared__ int ts[1024];
  const int t = threadIdx.x;
  int v = hist[t];
  ts[t] = v;
  __syncthreads();
  for (int off = 1; off < 1024; off <<= 1) {
    int u = (t >= off) ? ts[t - off] : 0;
    __syncthreads();
    ts[t] += u;
    __syncthreads();
  }
  offs[t] = ts[t] - v;
  if (t == 1023) offs[1024] = ts[t];
}

__global__ __launch_bounds__(256)
void bin_scatter(const float* __restrict__ pos, const int* __restrict__ cid,
                 const int* __restrict__ offs, int* __restrict__ cursor,
                 float* __restrict__ sx, float* __restrict__ sy,
                 int* __restrict__ sid, int n) {
  int i = blockIdx.x * 256 + threadIdx.x;
  if (i >= n) return;
  int c = cid[i];
  int p = atomicAdd(&cursor[c], 1);
  int slot = offs[c] + p;
  sx[slot] = pos[2 * i];
  sy[slot] = pos[2 * i + 1];
  sid[slot] = i;
}

// ---------------- FPS: per-thread chunk tops in LDS + single-wave reduce ----------------
template<int NN>
__device__ __forceinline__ unsigned ror16(unsigned v) {
  return (unsigned)__builtin_amdgcn_update_dpp(0, (int)v, 0x120 | NN, 0xF, 0xF, false);
}

// r3-style structure: thread t owns chunk [t*CHUNK, (t+1)*CHUNK) of the
// Morton-sorted points. Chunk top key (u64 = dist_bits<<32 | ~id) + coords in
// LDS ck/cp, written ONLY by the owner thread. Wave 0 reduces all NT tops
// each iteration (NT/64 loads/lane + 4 DPP ror + readlane finale).
template<int N, int NT, int NKEEP>
__global__ __launch_bounds__(NT, 1)
void fps_fast10(const float* __restrict__ pos0,
                const float* __restrict__ sx, const float* __restrict__ sy,
                const int* __restrict__ sid,
                int* __restrict__ perm, float* __restrict__ pos_out) {
  constexpr int CHUNK = N / NT;        // 32 (fps0) / 16 (fps1)
  const int t = threadIdx.x;
  const int base = t * CHUNK;

  __shared__ float pxl[N];             // transposed: pxl[j*NT + t]
  __shared__ float pyl[N];
  __shared__ unsigned long long ck[NT];
  __shared__ float2 cp[NT];
  __shared__ float bc[2];

  unsigned long long key[CHUNK];       // dist_bits<<32 | ~orig_id

  float cx = pos0[0], cy = pos0[1];
  if (t == 0) { perm[0] = 0; pos_out[0] = cx; pos_out[1] = cy; }

  float x0 = 3.4e38f, x1 = -3.4e38f, y0 = 3.4e38f, y1 = -3.4e38f;
  {
    unsigned long long best = 0; float bx = 0.f, by = 0.f;
    #pragma unroll
    for (int j = 0; j < CHUNK; ++j) {
      float qx = sx[base + j], qy = sy[base + j];
      unsigned uid = ~(unsigned)sid[base + j];
      pxl[j * NT + t] = qx; pyl[j * NT + t] = qy;
      x0 = fminf(x0, qx); x1 = fmaxf(x1, qx);
      y0 = fminf(y0, qy); y1 = fmaxf(y1, qy);
      float dx = __fsub_rn(qx, cx), dy = __fsub_rn(qy, cy);
      float nd = __fadd_rn(__fmul_rn(dx, dx), __fmul_rn(dy, dy));
      unsigned long long k = ((unsigned long long)__float_as_uint(nd) << 32) | uid;
      key[j] = k;
      if (k > best) { best = k; bx = qx; by = qy; }
    }
    ck[t] = best;
    cp[t] = make_float2(bx, by);
  }
  float cmax = __uint_as_float((unsigned)(ck[t] >> 32));
  __syncthreads();

  for (int i = 1; i < NKEEP; ++i) {
    // ---- single-wave reduce over NT chunk tops ----
    if (t < 64) {
      unsigned long long bk = 0;
      int sl = 0;
      #pragma unroll
      for (int j = 0; j < NT / 64; ++j) {
        unsigned long long k = ck[t + j * 64];
        if (k > bk) { bk = k; sl = t + j * 64; }
      }
      // 16-lane row reduce via DPP row_ror
      {
        unsigned hi, lo, ohi, olo; int os;
        hi = (unsigned)(bk >> 32); lo = (unsigned)bk;
        ohi = ror16<1>(hi); olo = ror16<1>(lo); os = (int)ror16<1>((unsigned)sl);
        { unsigned long long ok = ((unsigned long long)ohi << 32) | olo;
          if (ok > bk) { bk = ok; sl = os; } }
        hi = (unsigned)(bk >> 32); lo = (unsigned)bk;
        ohi = ror16<2>(hi); olo = ror16<2>(lo); os = (int)ror16<2>((unsigned)sl);
        { unsigned long long ok = ((unsigned long long)ohi << 32) | olo;
          if (ok > bk) { bk = ok; sl = os; } }
        hi = (unsigned)(bk >> 32); lo = (unsigned)bk;
        ohi = ror16<4>(hi); olo = ror16<4>(lo); os = (int)ror16<4>((unsigned)sl);
        { unsigned long long ok = ((unsigned long long)ohi << 32) | olo;
          if (ok > bk) { bk = ok; sl = os; } }
        hi = (unsigned)(bk >> 32); lo = (unsigned)bk;
        ohi = ror16<8>(hi); olo = ror16<8>(lo); os = (int)ror16<8>((unsigned)sl);
        { unsigned long long ok = ((unsigned long long)ohi << 32) | olo;
          if (ok > bk) { bk = ok; sl = os; } }
      }
      // cross-row combine via readlane
      unsigned hi = (unsigned)(bk >> 32), lo = (unsigned)bk;
      unsigned long long fb = 0; int fs = 0;
      #pragma unroll
      for (int r = 0; r < 4; ++r) {
        unsigned h = (unsigned)__builtin_amdgcn_readlane((int)hi, r * 16);
        unsigned l = (unsigned)__builtin_amdgcn_readlane((int)lo, r * 16);
        int s = __builtin_amdgcn_readlane(sl, r * 16);
        unsigned long long k = ((unsigned long long)h << 32) | l;
        if (k > fb) { fb = k; fs = s; }
      }
      if (t == 0) {
        float2 c = cp[fs];
        perm[i] = (int)(~(unsigned)fb);
        pos_out[2 * i] = c.x; pos_out[2 * i + 1] = c.y;
        bc[0] = c.x; bc[1] = c.y;
      }
    }
    __syncthreads();
    cx = bc[0]; cy = bc[1];

    // ---- per-thread prune + rescan (divergent, no wave gating) ----
    float mdx = fmaxf(fmaxf(__fsub_rn(x0, cx), __fsub_rn(cx, x1)), 0.f);
    float mdy = fmaxf(fmaxf(__fsub_rn(y0, cy), __fsub_rn(cy, y1)), 0.f);
    float mb = mdx * mdx + mdy * mdy;
    if (!(mb * 0.99999f > cmax)) {
      unsigned long long best = 0; float bx = 0.f, by = 0.f;
      #pragma unroll
      for (int j = 0; j < CHUNK; ++j) {
        float qx = pxl[j * NT + t], qy = pyl[j * NT + t];
        float dx = __fsub_rn(qx, cx), dy = __fsub_rn(qy, cy);
        float nd = __fadd_rn(__fmul_rn(dx, dx), __fmul_rn(dy, dy));
        unsigned long long nk =
            ((unsigned long long)__float_as_uint(nd) << 32) | (unsigned)key[j];
        if (nk < key[j]) key[j] = nk;
        if (key[j] > best) { best = key[j]; bx = qx; by = qy; }
      }
      ck[t] = best;
      cp[t] = make_float2(bx, by);
      cmax = __uint_as_float((unsigned)(best >> 32));
    }
    __syncthreads();
  }
}

// ---------------- row gather ----------------
__global__ __launch_bounds__(256)
void gather_rows(const float* __restrict__ xin, const int* __restrict__ perm,
                 float* __restrict__ xout, int n) {
  const int wid = threadIdx.x >> 6, lane = threadIdx.x & 63;
  const int i = blockIdx.x * 4 + wid;
  if (i >= n) return;
  const int s = perm[i];
  const float4* r = (const float4*)(xin + (size_t)s * HF);
  float4* o = (float4*)(xout + (size_t)i * HF);
  o[lane] = r[lane];
  o[64 + lane] = r[64 + lane];
}

// ---------------- kNN graph ----------------
template<int NPTS, int K>
__global__ __launch_bounds__(256)
void knn_graph_kernel(const float* __restrict__ pos, int* __restrict__ srcout) {
  __shared__ float sx[NPTS], sy[NPTS], ss[NPTS];
  const int tid = threadIdx.x;
  for (int idx = tid; idx < NPTS; idx += 256) {
    float x = pos[2 * idx], y = pos[2 * idx + 1];
    sx[idx] = x; sy[idx] = y;
    ss[idx] = __fadd_rn(__fmul_rn(x, x), __fmul_rn(y, y));
  }
  __syncthreads();
  const int q = blockIdx.x * 256 + tid;
  const float qx = sx[q], qy = sy[q], qs = ss[q];
  float bd[K]; int bi[K];
  #pragma unroll
  for (int m = 0; m < K; ++m) { bd[m] = 3.4e38f; bi[m] = 0; }
  for (int j = 0; j < NPTS; ++j) {
    if (j == q) continue;
    float dot = __fadd_rn(__fmul_rn(qx, sx[j]), __fmul_rn(qy, sy[j]));
    float d2 = fmaxf(__fsub_rn(__fadd_rn(qs, ss[j]), __fmul_rn(2.0f, dot)), 0.0f);
    if (d2 < bd[K - 1]) {
      bool pr[K];
      #pragma unroll
      for (int m = 0; m < K; ++m) pr[m] = (d2 < bd[m]);
      #pragma unroll
      for (int m = K - 1; m >= 1; --m) {
        bd[m] = pr[m] ? (pr[m - 1] ? bd[m - 1] : d2) : bd[m];
        bi[m] = pr[m] ? (pr[m - 1] ? bi[m - 1] : j) : bi[m];
      }
      if (pr[0]) { bd[0] = d2; bi[0] = j; }
    }
  }
  #pragma unroll
  for (int m = 0; m < K; ++m) srcout[q * K + m] = bi[m];
}

// ---------------- kNN interpolate ----------------
template<int NX, int K>
__global__ __launch_bounds__(256)
void interp_topk(const float* __restrict__ posy, const float* __restrict__ posx,
                 int* __restrict__ oidx, float* __restrict__ ow,
                 float* __restrict__ owsum) {
  __shared__ float sx[NX], sy[NX], ss[NX];
  const int tid = threadIdx.x;
  for (int idx = tid; idx < NX; idx += 256) {
    float x = posx[2 * idx], y = posx[2 * idx + 1];
    sx[idx] = x; sy[idx] = y;
    ss[idx] = __fadd_rn(__fmul_rn(x, x), __fmul_rn(y, y));
  }
  __syncthreads();
  const int q = blockIdx.x * 256 + tid;
  const float qx = posy[2 * q], qy = posy[2 * q + 1];
  const float qs = __fadd_rn(__fmul_rn(qx, qx), __fmul_rn(qy, qy));
  float bd[K]; int bi[K];
  #pragma unroll
  for (int m = 0; m < K; ++m) { bd[m] = 3.4e38f; bi[m] = 0; }
  for (int j = 0; j < NX; ++j) {
    float dot = __fadd_rn(__fmul_rn(qx, sx[j]), __fmul_rn(qy, sy[j]));
    float d2 = fmaxf(__fsub_rn(__fadd_rn(qs, ss[j]), __fmul_rn(2.0f, dot)), 0.0f);
    if (d2 < bd[K - 1]) {
      bool pr[K];
      #pragma unroll
      for (int m = 0; m < K; ++m) pr[m] = (d2 < bd[m]);
      #pragma unroll
      for (int m = K - 1; m >= 1; --m) {
        bd[m] = pr[m] ? (pr[m - 1] ? bd[m - 1] : d2) : bd[m];
        bi[m] = pr[m] ? (pr[m - 1] ? bi[m - 1] : j) : bi[m];
      }
      if (pr[0]) { bd[0] = d2; bi[0] = j; }
    }
  }
  float wsum = 0.f;
  #pragma unroll
  for (int m = 0; m < K; ++m) {
    float w = 1.0f / fmaxf(bd[m], 1e-16f);
    ow[q * K + m] = w;
    oidx[q * K + m] = bi[m];
    wsum = __fadd_rn(wsum, w);
  }
  owsum[q] = wsum;
}

template<int K>
__global__ __launch_bounds__(256)
void interp_combine(const float* __restrict__ xin, const int* __restrict__ idx,
                    const float* __restrict__ w, const float* __restrict__ wsum,
                    float* __restrict__ out, int ny) {
  const int wid = threadIdx.x >> 6, lane = threadIdx.x & 63;
  const int q = blockIdx.x * 4 + wid;
  if (q >= ny) return;
  float4 a0 = {0, 0, 0, 0}, a1 = {0, 0, 0, 0};
  #pragma unroll
  for (int m = 0; m < K; ++m) {
    const int s = idx[q * K + m];
    const float wk = w[q * K + m];
    const float4* r = (const float4*)(xin + (size_t)s * HF);
    a0 = f4fma(wk, r[lane], a0);
    a1 = f4fma(wk, r[64 + lane], a1);
  }
  const float inv = wsum[q];
  a0.x /= inv; a0.y /= inv; a0.z /= inv; a0.w /= inv;
  a1.x /= inv; a1.y /= inv; a1.z /= inv; a1.w /= inv;
  float4* o = (float4*)(out + (size_t)q * HF);
  o[lane] = a0; o[64 + lane] = a1;
}

// ---------------- launcher ----------------
extern "C" void kernel_launch(void* const* d_in, const int* in_sizes, int n_in,
                              void* d_out, int out_size, void* d_ws, size_t ws_size,
                              hipStream_t stream) {
  const float* x    = (const float*)d_in[0];
  const float* pos  = (const float*)d_in[1];
  const int*   ei   = (const int*)d_in[2];
  const float* Wd0  = (const float*)d_in[3];
  const float* bd0  = (const float*)d_in[4];
  const float* Wd1  = (const float*)d_in[5];
  const float* bd1  = (const float*)d_in[6];
  const float* Wu0  = (const float*)d_in[7];
  const float* bu0  = (const float*)d_in[8];
  const float* Wu1  = (const float*)d_in[9];
  const float* bu1  = (const float*)d_in[10];
  const float* Wl   = (const float*)d_in[11];
  const float* bl   = (const float*)d_in[12];
  float* out = (float*)d_out;

  char* ws = (char*)d_ws;
  size_t off = 0;
  auto alloc = [&](size_t bytes) -> char* {
    char* p = ws + off;
    off = (off + bytes + 255) & ~(size_t)255;
    return p;
  };
  float* bufA   = (float*)alloc((size_t)N0 * HF * 4);
  float* bufB   = (float*)alloc((size_t)N0 * HF * 4);
  float* bufC   = (float*)alloc((size_t)N1 * HF * 4);
  float* x2     = (float*)alloc((size_t)N2 * HF * 4);
  int*   offs0  = (int*)alloc((N0 + 1) * 4);
  int*   srcl0  = (int*)alloc(E0C * 4);
  int*   cnt    = (int*)alloc(N0 * 4);
  int*   cursor = (int*)alloc(N0 * 4);
  float* dinv0  = (float*)alloc(N0 * 4);
  int*   perm0  = (int*)alloc(N1 * 4);
  float* pos1   = (float*)alloc(N1 * 2 * 4);
  int*   src1   = (int*)alloc(N1 * 6 * 4);
  int*   perm1  = (int*)alloc(N2 * 4);
  float* pos2   = (float*)alloc(N2 * 2 * 4);
  int*   iidx   = (int*)alloc((size_t)N0 * 6 * 4);
  float* iw     = (float*)alloc((size_t)N0 * 6 * 4);
  float* iwsum  = (float*)alloc(N0 * 4);
  // binning scratch
  float* bsx    = (float*)alloc(N0 * 4);
  float* bsy    = (float*)alloc(N0 * 4);
  int*   bsid   = (int*)alloc(N0 * 4);
  int*   bcid   = (int*)alloc(N0 * 4);
  int*   bhist  = (int*)alloc(1024 * 4);
  int*   bcur   = (int*)alloc(1024 * 4);
  int*   boffs  = (int*)alloc(1025 * 4);

  float* h1   = bufB;
  float* x1f  = bufB + (size_t)N1 * HF;
  float* hu0  = bufB;
  float* xu0f = bufB + (size_t)N1 * HF;

  // level-0 CSR
  hipMemsetAsync(cnt, 0, N0 * 4, stream);
  hipMemsetAsync(cursor, 0, N0 * 4, stream);
  count_deg<<<E0C / 256, 256, 0, stream>>>(ei + E0C, cnt, E0C);
  scan_offsets<<<1, 1024, 0, stream>>>(cnt, offs0, dinv0);
  fill_csr<<<E0C / 256, 256, 0, stream>>>(ei, ei + E0C, offs0, cursor, srcl0, E0C);

  // bin pos (level 0) for FPS0
  hipMemsetAsync(bhist, 0, 1024 * 4, stream);
  hipMemsetAsync(bcur, 0, 1024 * 4, stream);
  bin_hist<<<N0 / 256, 256, 0, stream>>>(pos, bcid, bhist, N0);
  bin_scan<<<1, 1024, 0, stream>>>(bhist, boffs);
  bin_scatter<<<N0 / 256, 256, 0, stream>>>(pos, bcid, boffs, bcur, bsx, bsy, bsid, N0);

  // down 0
  gemm_f32<128, 64, 16><<<dim3(N0 / 128, HF / 64), 256, 0, stream>>>(
      x, Wd0, nullptr, bufA, N0, HF, FIN, 0);
  gcn_agg_csr<<<N0 / 4, 256, 0, stream>>>(bufA, offs0, srcl0, dinv0, bd0, bufB, N0);
  fps_fast10<N0, 512, N1><<<1, 512, 0, stream>>>(pos, bsx, bsy, bsid, perm0, pos1);
  gather_rows<<<N1 / 4, 256, 0, stream>>>(bufB, perm0, bufC, N1);
  knn_graph_kernel<N1, 6><<<N1 / 256, 256, 0, stream>>>(pos1, src1);

  // bin pos1 for FPS1
  hipMemsetAsync(bhist, 0, 1024 * 4, stream);
  hipMemsetAsync(bcur, 0, 1024 * 4, stream);
  bin_hist<<<N1 / 256, 256, 0, stream>>>(pos1, bcid, bhist, N1);
  bin_scan<<<1, 1024, 0, stream>>>(bhist, boffs);
  bin_scatter<<<N1 / 256, 256, 0, stream>>>(pos1, bcid, boffs, bcur, bsx, bsy, bsid, N1);

  // down 1
  gemm_f32<128, 64, 16><<<dim3(N1 / 128, HF / 64), 256, 0, stream>>>(
      bufC, Wd1, nullptr, h1, N1, HF, HF, 0);
  gcn_agg_knn<6><<<N1 / 4, 256, 0, stream>>>(h1, src1, bd1, x1f, N1);
  fps_fast10<N1, 256, N2><<<1, 256, 0, stream>>>(pos1, bsx, bsy, bsid, perm1, pos2);
  gather_rows<<<N2 / 4, 256, 0, stream>>>(x1f, perm1, x2, N2);

  // up 0
  interp_topk<N2, 6><<<N1 / 256, 256, 0, stream>>>(pos1, pos2, iidx, iw, iwsum);
  interp_combine<6><<<N1 / 4, 256, 0, stream>>>(x2, iidx, iw, iwsum, bufC, N1);
  gemm_f32<128, 64, 16><<<dim3(N1 / 128, HF / 64), 256, 0, stream>>>(
      bufC, Wu0, nullptr, hu0, N1, HF, HF, 0);
  gcn_agg_knn<6><<<N1 / 4, 256, 0, stream>>>(hu0, src1, bu0, xu0f, N1);

  // up 1
  interp_topk<N1, 6><<<N0 / 256, 256, 0, stream>>>(pos, pos1, iidx, iw, iwsum);
  interp_combine<6><<<N0 / 4, 256, 0, stream>>>(xu0f, iidx, iw, iwsum, bufA, N0);
  gemm_f32<128, 64, 16><<<dim3(N0 / 128, HF / 64), 256, 0, stream>>>(
      bufA, Wu1, nullptr, bufB, N0, HF, HF, 0);
  gcn_agg_csr<<<N0 / 4, 256, 0, stream>>>(bufB, offs0, srcl0, dinv0, bu1, bufA, N0);

  // final linear
  gemm_f32<128, 64, 16><<<dim3(N0 / 128, HF / 64), 256, 0, stream>>>(
      bufA, Wl, bl, out, N0, HF, HF, 1);
}

// Round 14
// 7855.647 us; speedup vs baseline: 1.3510x; 1.3510x over previous
//
#include <hip/hip_runtime.h>

#define N0 16384
#define N1 4096
#define N2 1024
#define E0C 131072
#define FIN 384
#define HF 512

// ---------------- helpers ----------------
__device__ inline float4 f4fma(float w, const float4 v, float4 a) {
  a.x = fmaf(w, v.x, a.x); a.y = fmaf(w, v.y, a.y);
  a.z = fmaf(w, v.z, a.z); a.w = fmaf(w, v.w, a.w);
  return a;
}

// ---------------- CSR build for level-0 random graph ----------------
__global__ __launch_bounds__(256)
void count_deg(const int* __restrict__ dst, int* __restrict__ cnt, int E) {
  int e = blockIdx.x * 256 + threadIdx.x;
  if (e < E) atomicAdd(&cnt[dst[e]], 1);
}

__global__ __launch_bounds__(1024)
void scan_offsets(const int* __restrict__ cnt, int* __restrict__ offs,
                  float* __restrict__ dinv) {
  __shared__ int ts[1024];
  const int t = threadIdx.x;
  int local[16];
  int sum = 0;
  #pragma unroll
  for (int j = 0; j < 16; ++j) { local[j] = cnt[t * 16 + j]; sum += local[j]; }
  ts[t] = sum;
  __syncthreads();
  for (int off = 1; off < 1024; off <<= 1) {
    int v = (t >= off) ? ts[t - off] : 0;
    __syncthreads();
    ts[t] += v;
    __syncthreads();
  }
  int run = ts[t] - sum;
  #pragma unroll
  for (int j = 0; j < 16; ++j) {
    offs[t * 16 + j] = run;
    dinv[t * 16 + j] = 1.0f / sqrtf((float)local[j] + 2.0f);
    run += local[j];
  }
  if (t == 1023) offs[N0] = run;
}

__global__ __launch_bounds__(256)
void fill_csr(const int* __restrict__ src, const int* __restrict__ dst,
              const int* __restrict__ offs, int* __restrict__ cursor,
              int* __restrict__ srcl, int E) {
  int e = blockIdx.x * 256 + threadIdx.x;
  if (e < E) {
    int d = dst[e];
    int p = atomicAdd(&cursor[d], 1);
    srcl[offs[d] + p] = src[e];
  }
}

// ---------------- fp32 GEMM ----------------
template<int BM, int BN, int BK>
__global__ __launch_bounds__(256)
void gemm_f32(const float* __restrict__ A, const float* __restrict__ W,
              const float* __restrict__ bias, float* __restrict__ C,
              int M, int N, int K, int addBias) {
  __shared__ float As[BK][BM + 4];
  __shared__ float Ws[BK][BN];
  const int tid = threadIdx.x;
  const int bm = blockIdx.x * BM;
  const int bn = blockIdx.y * BN;
  const int tx = tid & 15;
  const int ty = tid >> 4;
  float acc[8][4];
  #pragma unroll
  for (int i = 0; i < 8; ++i)
    #pragma unroll
    for (int j = 0; j < 4; ++j) acc[i][j] = 0.f;

  for (int k0 = 0; k0 < K; k0 += BK) {
    #pragma unroll
    for (int h = 0; h < (BM * BK) / (256 * 4); ++h) {
      int q = tid + h * 256;
      int r = q >> 2;
      int c = (q & 3) << 2;
      float4 v = *(const float4*)(A + (size_t)(bm + r) * K + k0 + c);
      As[c][r] = v.x; As[c + 1][r] = v.y; As[c + 2][r] = v.z; As[c + 3][r] = v.w;
    }
    {
      int kk = tid >> 4;
      int n = (tid & 15) << 2;
      *(float4*)(&Ws[kk][n]) = *(const float4*)(W + (size_t)(k0 + kk) * N + bn + n);
    }
    __syncthreads();
    #pragma unroll
    for (int kk = 0; kk < BK; ++kk) {
      float4 b4 = *(const float4*)(&Ws[kk][tx << 2]);
      float4 a0 = *(const float4*)(&As[kk][ty << 3]);
      float4 a1 = *(const float4*)(&As[kk][(ty << 3) + 4]);
      float a[8] = {a0.x, a0.y, a0.z, a0.w, a1.x, a1.y, a1.z, a1.w};
      float b[4] = {b4.x, b4.y, b4.z, b4.w};
      #pragma unroll
      for (int i = 0; i < 8; ++i)
        #pragma unroll
        for (int j = 0; j < 4; ++j)
          acc[i][j] = fmaf(a[i], b[j], acc[i][j]);
    }
    __syncthreads();
  }
  #pragma unroll
  for (int i = 0; i < 8; ++i) {
    int row = bm + (ty << 3) + i;
    float4 o = {acc[i][0], acc[i][1], acc[i][2], acc[i][3]};
    if (addBias) {
      const float4 bb = *(const float4*)(bias + bn + (tx << 2));
      o.x += bb.x; o.y += bb.y; o.z += bb.z; o.w += bb.w;
    }
    *(float4*)(C + (size_t)row * N + bn + (tx << 2)) = o;
  }
}

// ---------------- GCN aggregation (CSR) ----------------
__global__ __launch_bounds__(256)
void gcn_agg_csr(const float* __restrict__ h, const int* __restrict__ offs,
                 const int* __restrict__ srcl, const float* __restrict__ dinv,
                 const float* __restrict__ bias, float* __restrict__ out, int n) {
  const int wid = threadIdx.x >> 6, lane = threadIdx.x & 63;
  const int node = blockIdx.x * 4 + wid;
  if (node >= n) return;
  const float di = dinv[node];
  const int s0 = offs[node], s1 = offs[node + 1];
  float4 a0 = {0, 0, 0, 0}, a1 = {0, 0, 0, 0};
  for (int e = s0; e < s1; ++e) {
    const int s = srcl[e];
    const float w = dinv[s] * di;
    const float4* r = (const float4*)(h + (size_t)s * HF);
    a0 = f4fma(w, r[lane], a0);
    a1 = f4fma(w, r[64 + lane], a1);
  }
  const float sw = 2.0f * di * di;
  const float4* rs = (const float4*)(h + (size_t)node * HF);
  a0 = f4fma(sw, rs[lane], a0);
  a1 = f4fma(sw, rs[64 + lane], a1);
  const float4 b0 = *(const float4*)(bias + (lane << 2));
  const float4 b1 = *(const float4*)(bias + 256 + (lane << 2));
  a0.x = fmaxf(a0.x + b0.x, 0.f); a0.y = fmaxf(a0.y + b0.y, 0.f);
  a0.z = fmaxf(a0.z + b0.z, 0.f); a0.w = fmaxf(a0.w + b0.w, 0.f);
  a1.x = fmaxf(a1.x + b1.x, 0.f); a1.y = fmaxf(a1.y + b1.y, 0.f);
  a1.z = fmaxf(a1.z + b1.z, 0.f); a1.w = fmaxf(a1.w + b1.w, 0.f);
  float4* o = (float4*)(out + (size_t)node * HF);
  o[lane] = a0; o[64 + lane] = a1;
}

// ---------------- GCN aggregation (kNN) ----------------
template<int K>
__global__ __launch_bounds__(256)
void gcn_agg_knn(const float* __restrict__ h, const int* __restrict__ nbr,
                 const float* __restrict__ bias, float* __restrict__ out, int n) {
  const int wid = threadIdx.x >> 6, lane = threadIdx.x & 63;
  const int node = blockIdx.x * 4 + wid;
  if (node >= n) return;
  const float di = 1.0f / sqrtf((float)(K + 2));
  const float w = di * di;
  float4 a0 = {0, 0, 0, 0}, a1 = {0, 0, 0, 0};
  #pragma unroll
  for (int j = 0; j < K; ++j) {
    const int s = nbr[node * K + j];
    const float4* r = (const float4*)(h + (size_t)s * HF);
    a0 = f4fma(w, r[lane], a0);
    a1 = f4fma(w, r[64 + lane], a1);
  }
  const float sw = 2.0f * di * di;
  const float4* rs = (const float4*)(h + (size_t)node * HF);
  a0 = f4fma(sw, rs[lane], a0);
  a1 = f4fma(sw, rs[64 + lane], a1);
  const float4 b0 = *(const float4*)(bias + (lane << 2));
  const float4 b1 = *(const float4*)(bias + 256 + (lane << 2));
  a0.x = fmaxf(a0.x + b0.x, 0.f); a0.y = fmaxf(a0.y + b0.y, 0.f);
  a0.z = fmaxf(a0.z + b0.z, 0.f); a0.w = fmaxf(a0.w + b0.w, 0.f);
  a1.x = fmaxf(a1.x + b1.x, 0.f); a1.y = fmaxf(a1.y + b1.y, 0.f);
  a1.z = fmaxf(a1.z + b1.z, 0.f); a1.w = fmaxf(a1.w + b1.w, 0.f);
  float4* o = (float4*)(out + (size_t)node * HF);
  o[lane] = a0; o[64 + lane] = a1;
}

// ---------------- spatial binning (counting sort into Morton cells) ----------------
__device__ __forceinline__ unsigned part1by1(unsigned x) {
  x &= 0xFFFFu;
  x = (x | (x << 8)) & 0x00FF00FFu;
  x = (x | (x << 4)) & 0x0F0F0F0Fu;
  x = (x | (x << 2)) & 0x33333333u;
  x = (x | (x << 1)) & 0x55555555u;
  return x;
}

__global__ __launch_bounds__(256)
void bin_hist(const float* __restrict__ pos, int* __restrict__ cid,
              int* __restrict__ hist, int n) {
  int i = blockIdx.x * 256 + threadIdx.x;
  if (i >= n) return;
  float x = pos[2 * i], y = pos[2 * i + 1];
  int cxi = (int)(x * 0.32f); cxi = cxi < 0 ? 0 : (cxi > 31 ? 31 : cxi);
  int cyi = (int)(y * 0.32f); cyi = cyi < 0 ? 0 : (cyi > 31 ? 31 : cyi);
  int c = (int)(part1by1((unsigned)cxi) | (part1by1((unsigned)cyi) << 1));
  cid[i] = c;
  atomicAdd(&hist[c], 1);
}

__global__ __launch_bounds__(1024)
void bin_scan(const int* __restrict__ hist, int* __restrict__ offs) {
  __shared__ int ts[1024];
  const int t = threadIdx.x;
  int v = hist[t];
  ts[t] = v;
  __syncthreads();
  for (int off = 1; off < 1024; off <<= 1) {
    int u = (t >= off) ? ts[t - off] : 0;
    __syncthreads();
    ts[t] += u;
    __syncthreads();
  }
  offs[t] = ts[t] - v;
  if (t == 1023) offs[1024] = ts[t];
}

__global__ __launch_bounds__(256)
void bin_scatter(const float* __restrict__ pos, const int* __restrict__ cid,
                 const int* __restrict__ offs, int* __restrict__ cursor,
                 float* __restrict__ sx, float* __restrict__ sy,
                 int* __restrict__ sid, int n) {
  int i = blockIdx.x * 256 + threadIdx.x;
  if (i >= n) return;
  int c = cid[i];
  int p = atomicAdd(&cursor[c], 1);
  int slot = offs[c] + p;
  sx[slot] = pos[2 * i];
  sy[slot] = pos[2 * i + 1];
  sid[slot] = i;
}

// ---------------- FPS: Morton-cell-ALIGNED blocks, keys in registers ----------------
template<int NN>
__device__ __forceinline__ unsigned ror16(unsigned v) {
  return (unsigned)__builtin_amdgcn_update_dpp(0, (int)v, 0x120 | NN, 0xF, 0xF, false);
}

__device__ __forceinline__ void kcmp(unsigned& hi, unsigned& lo, float& x, float& y,
                                     unsigned ohi, unsigned olo, float ox, float oy) {
  unsigned long long a = ((unsigned long long)hi << 32) | lo;
  unsigned long long b = ((unsigned long long)ohi << 32) | olo;
  if (b > a) { hi = ohi; lo = olo; x = ox; y = oy; }
}

#define ROR_STEP(NN) { \
    unsigned ohi_ = ror16<NN>(hi), olo_ = ror16<NN>(lo); \
    unsigned ox_ = ror16<NN>(__float_as_uint(x)), oy_ = ror16<NN>(__float_as_uint(y)); \
    kcmp(hi, lo, x, y, ohi_, olo_, __uint_as_float(ox_), __uint_as_float(oy_)); }

// 64-lane wave reduce of (key,x,y) -> uniform wave max in all lanes
__device__ __forceinline__ void wave_entry_reduce(
    unsigned long long ckey, float ccx, float ccy, int t, float4* wsc,
    unsigned& ehi, unsigned& elo, float& ex, float& ey) {
  unsigned hi = (unsigned)(ckey >> 32), lo = (unsigned)ckey;
  float x = ccx, y = ccy;
  ROR_STEP(1) ROR_STEP(2) ROR_STEP(4) ROR_STEP(8)
  if ((t & 15) == 0)
    wsc[(t >> 4) & 3] = make_float4(__uint_as_float(hi), __uint_as_float(lo), x, y);
  float4 a0 = wsc[0], a1 = wsc[1], a2 = wsc[2], a3 = wsc[3];
  hi = __float_as_uint(a0.x); lo = __float_as_uint(a0.y); x = a0.z; y = a0.w;
  kcmp(hi, lo, x, y, __float_as_uint(a1.x), __float_as_uint(a1.y), a1.z, a1.w);
  kcmp(hi, lo, x, y, __float_as_uint(a2.x), __float_as_uint(a2.y), a2.z, a2.w);
  kcmp(hi, lo, x, y, __float_as_uint(a3.x), __float_as_uint(a3.y), a3.z, a3.w);
  ehi = hi; elo = lo; ex = x; ey = y;
}

// Each wave owns ONE Morton-cell-aligned block: cells [wid*CPB, (wid+1)*CPB).
// Per-lane padded to SUBMAX points; sentinel key 0 never wins and never updates.
template<int N, int NT, int CPB, int SUBMAX, int NKEEP>
__global__ __launch_bounds__(NT, 1)
void fps_fast7(const float* __restrict__ pos0,
               const float* __restrict__ sx, const float* __restrict__ sy,
               const int* __restrict__ sid, const int* __restrict__ coffs,
               int* __restrict__ perm, float* __restrict__ pos_out) {
  constexpr int NW = NT / 64;
  const int t = threadIdx.x, wid = t >> 6, lane = t & 63;

  __shared__ float2 pp[N];             // linear, sorted order
  __shared__ float4 ebuf[2][NW];
  __shared__ float4 wscr[NW][4];

  unsigned long long key[SUBMAX];      // dist_bits<<32 | ~orig_id; 0 = invalid

  const int start = coffs[wid * CPB];
  const int end   = coffs[wid * CPB + CPB];
  const int base  = start + lane;

  float cx = pos0[0], cy = pos0[1];
  if (t == 0) { perm[0] = 0; pos_out[0] = cx; pos_out[1] = cy; }

  float x0 = 3.4e38f, x1 = -3.4e38f, y0 = 3.4e38f, y1 = -3.4e38f;
  unsigned long long ckey = 0; float ccx = 0.f, ccy = 0.f;
  #pragma unroll
  for (int j = 0; j < SUBMAX; ++j) {
    int idx = base + j * 64;
    bool v = idx < end;
    int ridx = idx < (N - 1) ? idx : (N - 1);
    float qx = sx[ridx], qy = sy[ridx];
    unsigned uid = ~(unsigned)sid[ridx];
    if (v) {
      pp[idx] = make_float2(qx, qy);
      x0 = fminf(x0, qx); x1 = fmaxf(x1, qx);
      y0 = fminf(y0, qy); y1 = fmaxf(y1, qy);
    }
    float dx = __fsub_rn(qx, cx), dy = __fsub_rn(qy, cy);
    float nd = __fadd_rn(__fmul_rn(dx, dx), __fmul_rn(dy, dy));
    unsigned long long k =
        v ? (((unsigned long long)__float_as_uint(nd) << 32) | uid) : 0ull;
    key[j] = k;
    if (k > ckey) { ckey = k; ccx = qx; ccy = qy; }
  }

  // wave bbox == block bbox (uniform after reduce)
  #pragma unroll
  for (int m = 1; m < 64; m <<= 1) {
    x0 = fminf(x0, __shfl_xor(x0, m)); x1 = fmaxf(x1, __shfl_xor(x1, m));
    y0 = fminf(y0, __shfl_xor(y0, m)); y1 = fmaxf(y1, __shfl_xor(y1, m));
  }

  unsigned ehi, elo; float ex, ey;
  wave_entry_reduce(ckey, ccx, ccy, t, wscr[wid], ehi, elo, ex, ey);
  if (lane == 0)
    ebuf[0][wid] = make_float4(__uint_as_float(ehi), __uint_as_float(elo), ex, ey);
  __syncthreads();

  int p = 0;
  for (int i = 1; i < NKEEP; ++i) {
    // ---- all-lane tournament over NW entries ----
    float4 e = ebuf[p][t & (NW - 1)];
    unsigned hi = __float_as_uint(e.x), lo = __float_as_uint(e.y);
    float x = e.z, y = e.w;
    ROR_STEP(1)
    if constexpr (NW >= 4)  { ROR_STEP(2) }
    if constexpr (NW >= 8)  { ROR_STEP(4) }
    if constexpr (NW >= 16) { ROR_STEP(8) }
    if (t == 0) {
      perm[i] = (int)(~lo);
      pos_out[2 * i] = x; pos_out[2 * i + 1] = y;
    }
    cx = x; cy = y;

    // ---- block-level skip: uniform branch, compact aligned bbox ----
    float mdx = fmaxf(fmaxf(__fsub_rn(x0, cx), __fsub_rn(cx, x1)), 0.f);
    float mdy = fmaxf(fmaxf(__fsub_rn(y0, cy), __fsub_rn(cy, y1)), 0.f);
    float mb = mdx * mdx + mdy * mdy;
    if (!(mb * 0.99999f > __uint_as_float(ehi))) {
      unsigned long long bk = 0; float bx = 0.f, by = 0.f;
      #pragma unroll
      for (int j = 0; j < SUBMAX; ++j) {
        int idx = base + j * 64;
        int ridx = idx < (N - 1) ? idx : (N - 1);
        float2 q = pp[ridx];
        float dx = __fsub_rn(q.x, cx), dy = __fsub_rn(q.y, cy);
        float nd = __fadd_rn(__fmul_rn(dx, dx), __fmul_rn(dy, dy));
        unsigned long long nk =
            ((unsigned long long)__float_as_uint(nd) << 32) | (unsigned)key[j];
        if (nk < key[j]) key[j] = nk;
        if (key[j] > bk) { bk = key[j]; bx = q.x; by = q.y; }
      }
      wave_entry_reduce(bk, bx, by, t, wscr[wid], ehi, elo, ex, ey);
    }
    if (lane == 0)
      ebuf[p ^ 1][wid] = make_float4(__uint_as_float(ehi), __uint_as_float(elo), ex, ey);
    __syncthreads();
    p ^= 1;
  }
}

// ---------------- row gather ----------------
__global__ __launch_bounds__(256)
void gather_rows(const float* __restrict__ xin, const int* __restrict__ perm,
                 float* __restrict__ xout, int n) {
  const int wid = threadIdx.x >> 6, lane = threadIdx.x & 63;
  const int i = blockIdx.x * 4 + wid;
  if (i >= n) return;
  const int s = perm[i];
  const float4* r = (const float4*)(xin + (size_t)s * HF);
  float4* o = (float4*)(xout + (size_t)i * HF);
  o[lane] = r[lane];
  o[64 + lane] = r[64 + lane];
}

// ---------------- kNN graph ----------------
template<int NPTS, int K>
__global__ __launch_bounds__(256)
void knn_graph_kernel(const float* __restrict__ pos, int* __restrict__ srcout) {
  __shared__ float sx[NPTS], sy[NPTS], ss[NPTS];
  const int tid = threadIdx.x;
  for (int idx = tid; idx < NPTS; idx += 256) {
    float x = pos[2 * idx], y = pos[2 * idx + 1];
    sx[idx] = x; sy[idx] = y;
    ss[idx] = __fadd_rn(__fmul_rn(x, x), __fmul_rn(y, y));
  }
  __syncthreads();
  const int q = blockIdx.x * 256 + tid;
  const float qx = sx[q], qy = sy[q], qs = ss[q];
  float bd[K]; int bi[K];
  #pragma unroll
  for (int m = 0; m < K; ++m) { bd[m] = 3.4e38f; bi[m] = 0; }
  for (int j = 0; j < NPTS; ++j) {
    if (j == q) continue;
    float dot = __fadd_rn(__fmul_rn(qx, sx[j]), __fmul_rn(qy, sy[j]));
    float d2 = fmaxf(__fsub_rn(__fadd_rn(qs, ss[j]), __fmul_rn(2.0f, dot)), 0.0f);
    if (d2 < bd[K - 1]) {
      bool pr[K];
      #pragma unroll
      for (int m = 0; m < K; ++m) pr[m] = (d2 < bd[m]);
      #pragma unroll
      for (int m = K - 1; m >= 1; --m) {
        bd[m] = pr[m] ? (pr[m - 1] ? bd[m - 1] : d2) : bd[m];
        bi[m] = pr[m] ? (pr[m - 1] ? bi[m - 1] : j) : bi[m];
      }
      if (pr[0]) { bd[0] = d2; bi[0] = j; }
    }
  }
  #pragma unroll
  for (int m = 0; m < K; ++m) srcout[q * K + m] = bi[m];
}

// ---------------- kNN interpolate ----------------
template<int NX, int K>
__global__ __launch_bounds__(256)
void interp_topk(const float* __restrict__ posy, const float* __restrict__ posx,
                 int* __restrict__ oidx, float* __restrict__ ow,
                 float* __restrict__ owsum) {
  __shared__ float sx[NX], sy[NX], ss[NX];
  const int tid = threadIdx.x;
  for (int idx = tid; idx < NX; idx += 256) {
    float x = posx[2 * idx], y = posx[2 * idx + 1];
    sx[idx] = x; sy[idx] = y;
    ss[idx] = __fadd_rn(__fmul_rn(x, x), __fmul_rn(y, y));
  }
  __syncthreads();
  const int q = blockIdx.x * 256 + tid;
  const float qx = posy[2 * q], qy = posy[2 * q + 1];
  const float qs = __fadd_rn(__fmul_rn(qx, qx), __fmul_rn(qy, qy));
  float bd[K]; int bi[K];
  #pragma unroll
  for (int m = 0; m < K; ++m) { bd[m] = 3.4e38f; bi[m] = 0; }
  for (int j = 0; j < NX; ++j) {
    float dot = __fadd_rn(__fmul_rn(qx, sx[j]), __fmul_rn(qy, sy[j]));
    float d2 = fmaxf(__fsub_rn(__fadd_rn(qs, ss[j]), __fmul_rn(2.0f, dot)), 0.0f);
    if (d2 < bd[K - 1]) {
      bool pr[K];
      #pragma unroll
      for (int m = 0; m < K; ++m) pr[m] = (d2 < bd[m]);
      #pragma unroll
      for (int m = K - 1; m >= 1; --m) {
        bd[m] = pr[m] ? (pr[m - 1] ? bd[m - 1] : d2) : bd[m];
        bi[m] = pr[m] ? (pr[m - 1] ? bi[m - 1] : j) : bi[m];
      }
      if (pr[0]) { bd[0] = d2; bi[0] = j; }
    }
  }
  float wsum = 0.f;
  #pragma unroll
  for (int m = 0; m < K; ++m) {
    float w = 1.0f / fmaxf(bd[m], 1e-16f);
    ow[q * K + m] = w;
    oidx[q * K + m] = bi[m];
    wsum = __fadd_rn(wsum, w);
  }
  owsum[q] = wsum;
}

template<int K>
__global__ __launch_bounds__(256)
void interp_combine(const float* __restrict__ xin, const int* __restrict__ idx,
                    const float* __restrict__ w, const float* __restrict__ wsum,
                    float* __restrict__ out, int ny) {
  const int wid = threadIdx.x >> 6, lane = threadIdx.x & 63;
  const int q = blockIdx.x * 4 + wid;
  if (q >= ny) return;
  float4 a0 = {0, 0, 0, 0}, a1 = {0, 0, 0, 0};
  #pragma unroll
  for (int m = 0; m < K; ++m) {
    const int s = idx[q * K + m];
    const float wk = w[q * K + m];
    const float4* r = (const float4*)(xin + (size_t)s * HF);
    a0 = f4fma(wk, r[lane], a0);
    a1 = f4fma(wk, r[64 + lane], a1);
  }
  const float inv = wsum[q];
  a0.x /= inv; a0.y /= inv; a0.z /= inv; a0.w /= inv;
  a1.x /= inv; a1.y /= inv; a1.z /= inv; a1.w /= inv;
  float4* o = (float4*)(out + (size_t)q * HF);
  o[lane] = a0; o[64 + lane] = a1;
}

// ---------------- launcher ----------------
extern "C" void kernel_launch(void* const* d_in, const int* in_sizes, int n_in,
                              void* d_out, int out_size, void* d_ws, size_t ws_size,
                              hipStream_t stream) {
  const float* x    = (const float*)d_in[0];
  const float* pos  = (const float*)d_in[1];
  const int*   ei   = (const int*)d_in[2];
  const float* Wd0  = (const float*)d_in[3];
  const float* bd0  = (const float*)d_in[4];
  const float* Wd1  = (const float*)d_in[5];
  const float* bd1  = (const float*)d_in[6];
  const float* Wu0  = (const float*)d_in[7];
  const float* bu0  = (const float*)d_in[8];
  const float* Wu1  = (const float*)d_in[9];
  const float* bu1  = (const float*)d_in[10];
  const float* Wl   = (const float*)d_in[11];
  const float* bl   = (const float*)d_in[12];
  float* out = (float*)d_out;

  char* ws = (char*)d_ws;
  size_t off = 0;
  auto alloc = [&](size_t bytes) -> char* {
    char* p = ws + off;
    off = (off + bytes + 255) & ~(size_t)255;
    return p;
  };
  float* bufA   = (float*)alloc((size_t)N0 * HF * 4);
  float* bufB   = (float*)alloc((size_t)N0 * HF * 4);
  float* bufC   = (float*)alloc((size_t)N1 * HF * 4);
  float* x2     = (float*)alloc((size_t)N2 * HF * 4);
  int*   offs0  = (int*)alloc((N0 + 1) * 4);
  int*   srcl0  = (int*)alloc(E0C * 4);
  int*   cnt    = (int*)alloc(N0 * 4);
  int*   cursor = (int*)alloc(N0 * 4);
  float* dinv0  = (float*)alloc(N0 * 4);
  int*   perm0  = (int*)alloc(N1 * 4);
  float* pos1   = (float*)alloc(N1 * 2 * 4);
  int*   src1   = (int*)alloc(N1 * 6 * 4);
  int*   perm1  = (int*)alloc(N2 * 4);
  float* pos2   = (float*)alloc(N2 * 2 * 4);
  int*   iidx   = (int*)alloc((size_t)N0 * 6 * 4);
  float* iw     = (float*)alloc((size_t)N0 * 6 * 4);
  float* iwsum  = (float*)alloc(N0 * 4);
  // binning scratch
  float* bsx    = (float*)alloc(N0 * 4);
  float* bsy    = (float*)alloc(N0 * 4);
  int*   bsid   = (int*)alloc(N0 * 4);
  int*   bcid   = (int*)alloc(N0 * 4);
  int*   bhist  = (int*)alloc(1024 * 4);
  int*   bcur   = (int*)alloc(1024 * 4);
  int*   boffs  = (int*)alloc(1025 * 4);

  float* h1   = bufB;
  float* x1f  = bufB + (size_t)N1 * HF;
  float* hu0  = bufB;
  float* xu0f = bufB + (size_t)N1 * HF;

  // level-0 CSR
  hipMemsetAsync(cnt, 0, N0 * 4, stream);
  hipMemsetAsync(cursor, 0, N0 * 4, stream);
  count_deg<<<E0C / 256, 256, 0, stream>>>(ei + E0C, cnt, E0C);
  scan_offsets<<<1, 1024, 0, stream>>>(cnt, offs0, dinv0);
  fill_csr<<<E0C / 256, 256, 0, stream>>>(ei, ei + E0C, offs0, cursor, srcl0, E0C);

  // bin pos (level 0) for FPS0
  hipMemsetAsync(bhist, 0, 1024 * 4, stream);
  hipMemsetAsync(bcur, 0, 1024 * 4, stream);
  bin_hist<<<N0 / 256, 256, 0, stream>>>(pos, bcid, bhist, N0);
  bin_scan<<<1, 1024, 0, stream>>>(bhist, boffs);
  bin_scatter<<<N0 / 256, 256, 0, stream>>>(pos, bcid, boffs, bcur, bsx, bsy, bsid, N0);

  // down 0
  gemm_f32<128, 64, 16><<<dim3(N0 / 128, HF / 64), 256, 0, stream>>>(
      x, Wd0, nullptr, bufA, N0, HF, FIN, 0);
  gcn_agg_csr<<<N0 / 4, 256, 0, stream>>>(bufA, offs0, srcl0, dinv0, bd0, bufB, N0);
  fps_fast7<N0, 1024, 64, 19, N1><<<1, 1024, 0, stream>>>(pos, bsx, bsy, bsid, boffs, perm0, pos1);
  gather_rows<<<N1 / 4, 256, 0, stream>>>(bufB, perm0, bufC, N1);
  knn_graph_kernel<N1, 6><<<N1 / 256, 256, 0, stream>>>(pos1, src1);

  // bin pos1 for FPS1
  hipMemsetAsync(bhist, 0, 1024 * 4, stream);
  hipMemsetAsync(bcur, 0, 1024 * 4, stream);
  bin_hist<<<N1 / 256, 256, 0, stream>>>(pos1, bcid, bhist, N1);
  bin_scan<<<1, 1024, 0, stream>>>(bhist, boffs);
  bin_scatter<<<N1 / 256, 256, 0, stream>>>(pos1, bcid, boffs, bcur, bsx, bsy, bsid, N1);

  // down 1
  gemm_f32<128, 64, 16><<<dim3(N1 / 128, HF / 64), 256, 0, stream>>>(
      bufC, Wd1, nullptr, h1, N1, HF, HF, 0);
  gcn_agg_knn<6><<<N1 / 4, 256, 0, stream>>>(h1, src1, bd1, x1f, N1);
  fps_fast7<N1, 512, 128, 10, N2><<<1, 512, 0, stream>>>(pos1, bsx, bsy, bsid, boffs, perm1, pos2);
  gather_rows<<<N2 / 4, 256, 0, stream>>>(x1f, perm1, x2, N2);

  // up 0
  interp_topk<N2, 6><<<N1 / 256, 256, 0, stream>>>(pos1, pos2, iidx, iw, iwsum);
  interp_combine<6><<<N1 / 4, 256, 0, stream>>>(x2, iidx, iw, iwsum, bufC, N1);
  gemm_f32<128, 64, 16><<<dim3(N1 / 128, HF / 64), 256, 0, stream>>>(
      bufC, Wu0, nullptr, hu0, N1, HF, HF, 0);
  gcn_agg_knn<6><<<N1 / 4, 256, 0, stream>>>(hu0, src1, bu0, xu0f, N1);

  // up 1
  interp_topk<N1, 6><<<N0 / 256, 256, 0, stream>>>(pos, pos1, iidx, iw, iwsum);
  interp_combine<6><<<N0 / 4, 256, 0, stream>>>(xu0f, iidx, iw, iwsum, bufA, N0);
  gemm_f32<128, 64, 16><<<dim3(N0 / 128, HF / 64), 256, 0, stream>>>(
      bufA, Wu1, nullptr, bufB, N0, HF, HF, 0);
  gcn_agg_csr<<<N0 / 4, 256, 0, stream>>>(bufB, offs0, srcl0, dinv0, bu1, bufA, N0);

  // final linear
  gemm_f32<128, 64, 16><<<dim3(N0 / 128, HF / 64), 256, 0, stream>>>(
      bufA, Wl, bl, out, N0, HF, HF, 1);
}